// Round 1
// baseline (44.878 us; speedup 1.0000x reference)
//
#include <hip/hip_runtime.h>
#include <hip/hip_bf16.h>
#include <stdint.h>

// VectorQuantizer: N=16384 vectors (D=64), K=8192 codes.
// score[n][k] = z_n.w_k - 0.5*||w_k||^2 (monotone in distance); idx = argmax.
// out[0..1048576) = quantized NCHW ; out[1048576] = 0.25*mse ; out[1048577] = mse

typedef __bf16 bf16x8 __attribute__((ext_vector_type(8)));
typedef float f32x16 __attribute__((ext_vector_type(16)));

// ---------------- prep: wbf = bf16(w), wnneg = -0.5||w||^2, zero loss slots
__global__ __launch_bounds__(256)
void vq_prep(const float* __restrict__ w, __bf16* __restrict__ wbf,
             float* __restrict__ wnneg, float* __restrict__ out)
{
  const int i = blockIdx.x * 256 + threadIdx.x;   // 2048 blocks x 256
  const float v = w[i];
  wbf[i] = (__bf16)v;
  float s = v * v;
#pragma unroll
  for (int m = 1; m < 64; m <<= 1) s += __shfl_xor(s, m);
  if ((threadIdx.x & 63) == 0) wnneg[i >> 6] = -0.5f * s;
  if (blockIdx.x == 0 && threadIdx.x < 2) out[1048576 + threadIdx.x] = 0.0f;
}

// ---------------- argmax: pipelined (counted vmcnt, NBUF=3), R=4 row-tiles/wave
// grid 512: ksp = bid&7 (1024-code slice -> XCD-local L2), zgrp = bid>>3 (256 rows)
// 8 waves: ch = wv>>1 (code quarter, 256 codes), rg = wv&1 (row half, 128 rows)
// publish: per-block LDS combine of the 4 ch-quarters, then ONE plain store per
// row into cand[ksp][n] (no global atomics, no cand zeroing).
__global__ __launch_bounds__(512, 2)
void vq_argmax(const float* __restrict__ z, const __bf16* __restrict__ wbf,
               const float* __restrict__ wnneg, float* __restrict__ cand)
{
  __shared__ __align__(16) char bufs[3][16384];
  __shared__ __align__(16) float wnl[1024];
  const int t = threadIdx.x;
  const int lane = t & 63, wv = t >> 6;
  const int hi = lane >> 5, hi4 = hi << 2, rA = lane & 31;
  const int ksp = blockIdx.x & 7, zgrp = blockIdx.x >> 3;
  const int kbase = ksp << 10;
  const int b = zgrp >> 2;
  const int hw0 = (zgrp & 3) << 8;
  const int ch = wv >> 1, rg = wv & 1;

  // stage -0.5||w||^2 slice (4 KB)
  ((float2*)wnl)[t] = ((const float2*)(wnneg + kbase))[t];
  asm volatile("s_waitcnt lgkmcnt(0)" ::: "memory");

  // pipeline stages: s=0..3 z-chunks (16 d-rows each), s=4..11 w-steps (4x32 codes)
  auto STAGE = [&](int s) {
    char* buf = &bufs[s % 3][0];
    if (s < 4) {
      // z chunk: d in [16s,16s+16), 256 hw window; 2 x 8KB halves
      const char* src = (const char*)z
          + (((size_t)((b << 6) + (s << 4) + wv)) << 12) + (hw0 << 2) + (lane << 4);
      __builtin_amdgcn_global_load_lds(
          (const __attribute__((address_space(1))) void*)src,
          (__attribute__((address_space(3))) void*)(buf + (wv << 10)), 16, 0, 0);
      __builtin_amdgcn_global_load_lds(
          (const __attribute__((address_space(1))) void*)(src + ((size_t)8 << 12)),
          (__attribute__((address_space(3))) void*)(buf + 8192 + (wv << 10)), 16, 0, 0);
    } else {
      // w step: 4 quarter-tiles of 32 codes, pre-swizzled source (XOR row&7 into col16)
      const int st = s - 4;
      const int tt = t & 255;
      const int row = tt >> 3, slot = (tt & 7) ^ (row & 7);
      const int q0 = t >> 8, q1 = q0 + 2;
      const char* wb = (const char*)wbf;
      const char* s0 = wb + (((size_t)(kbase + (q0 << 8) + (st << 5) + row)) << 7) + (slot << 4);
      const char* s1 = wb + (((size_t)(kbase + (q1 << 8) + (st << 5) + row)) << 7) + (slot << 4);
      char* d0 = buf + (q0 << 12) + ((wv & 3) << 10);
      char* d1 = buf + (q1 << 12) + ((wv & 3) << 10);
      __builtin_amdgcn_global_load_lds((const __attribute__((address_space(1))) void*)s0,
          (__attribute__((address_space(3))) void*)d0, 16, 0, 0);
      __builtin_amdgcn_global_load_lds((const __attribute__((address_space(1))) void*)s1,
          (__attribute__((address_space(3))) void*)d1, 16, 0, 0);
    }
  };

  STAGE(0); STAGE(1);

  // ---- z transpose phase (iters 0..3): build B fragments in registers
  bf16x8 zf[4][4];   // [row-tile][ks]
#pragma unroll
  for (int c = 0; c < 4; ++c) {
    asm volatile("s_waitcnt vmcnt(2)" ::: "memory");   // stage c done, c+1 in flight
    asm volatile("s_barrier" ::: "memory");
    const float* zp = (const float*)(&bufs[c % 3][0] + (hi << 13));
#pragma unroll
    for (int nt = 0; nt < 4; ++nt) {
      const int nl = (rg << 7) + (nt << 5) + rA;
      bf16x8 zv;
#pragma unroll
      for (int j = 0; j < 8; ++j) zv[j] = (__bf16)zp[(j << 8) + nl];
      zf[nt][c] = zv;
    }
    STAGE(c + 2);
  }

  // ---- main w phase (iters 4..11): 32 codes x 4 row-tiles per iter
  // Branchless packed argmax: score truncated to 10 mantissa bits, code id in
  // bits 0..12 (id bits disjoint from khw bits, verified: pat={0,1,3,4}, hi4=bit2,
  // kloc/kbase >= bit5). One v_and_or_b32 per element + max3 tree.
  float bestpk[4] = {-3.0e38f, -3.0e38f, -3.0e38f, -3.0e38f};

#pragma unroll 1
  for (int i = 4; i < 12; ++i) {
    if (i < 11) asm volatile("s_waitcnt vmcnt(2)" ::: "memory");
    else        asm volatile("s_waitcnt vmcnt(0)" ::: "memory");
    asm volatile("s_barrier" ::: "memory");
    const int st = i - 4;
    const char* tb = &bufs[i % 3][0] + (ch << 12);

    bf16x8 af[4];
#pragma unroll
    for (int ks = 0; ks < 4; ++ks) {
      const int c16 = (ks << 1) + hi;
      af[ks] = *(const bf16x8*)(tb + (rA << 7) + ((c16 ^ (rA & 7)) << 4));
    }

    const int kloc = (ch << 8) + (st << 5);
    f32x16 acc[4];
#pragma unroll
    for (int nt = 0; nt < 4; ++nt) {
      const float4 q0 = *(const float4*)(wnl + kloc + hi4);
      const float4 q1 = *(const float4*)(wnl + kloc + 8 + hi4);
      const float4 q2 = *(const float4*)(wnl + kloc + 16 + hi4);
      const float4 q3 = *(const float4*)(wnl + kloc + 24 + hi4);
      acc[nt] = (f32x16){q0.x, q0.y, q0.z, q0.w, q1.x, q1.y, q1.z, q1.w,
                         q2.x, q2.y, q2.z, q2.w, q3.x, q3.y, q3.z, q3.w};
    }
#pragma unroll
    for (int ks = 0; ks < 4; ++ks) {
#pragma unroll
      for (int nt = 0; nt < 4; ++nt)
        acc[nt] = __builtin_amdgcn_mfma_f32_32x32x16_bf16(af[ks], zf[nt][ks], acc[nt], 0, 0, 0);
    }

    const unsigned khw = (unsigned)(kbase + kloc + hi4);
#pragma unroll
    for (int nt = 0; nt < 4; ++nt) {
      const f32x16 a = acc[nt];
      float pk[16];
#pragma unroll
      for (int r = 0; r < 16; ++r) {
        const unsigned id = khw + (unsigned)((r & 3) + ((r >> 2) << 3)); // CSE'd across nt
        pk[r] = __uint_as_float((__float_as_uint(a[r]) & 0xFFFFE000u) | id);
      }
      const float g0 = fmaxf(fmaxf(pk[0], pk[1]), pk[2]);
      const float g1 = fmaxf(fmaxf(pk[3], pk[4]), pk[5]);
      const float g2 = fmaxf(fmaxf(pk[6], pk[7]), pk[8]);
      const float g3 = fmaxf(fmaxf(pk[9], pk[10]), pk[11]);
      const float g4 = fmaxf(fmaxf(pk[12], pk[13]), pk[14]);
      const float h0 = fmaxf(fmaxf(g0, g1), g2);
      const float h1 = fmaxf(fmaxf(g3, g4), pk[15]);
      bestpk[nt] = fmaxf(bestpk[nt], fmaxf(h0, h1));
    }
    if (i < 10) STAGE(i + 2);
  }

  // combine hi halves (lanes l, l+32 hold the same z-row), then combine the 4
  // ch-quarters through LDS (reuse wnl) and publish with ONE plain store/row.
  float bp4[4];
#pragma unroll
  for (int nt = 0; nt < 4; ++nt)
    bp4[nt] = fmaxf(bestpk[nt], __shfl_down(bestpk[nt], 32));

  __syncthreads();                 // all waves done reading wnl; safe to reuse
  if (lane < 32) {
#pragma unroll
    for (int nt = 0; nt < 4; ++nt)
      wnl[(ch << 8) + (rg << 7) + (nt << 5) + rA] = bp4[nt];
  }
  __syncthreads();
  if (t < 256) {
    const float m = fmaxf(fmaxf(wnl[t], wnl[256 + t]),
                          fmaxf(wnl[512 + t], wnl[768 + t]));
    cand[(ksp << 14) + (zgrp << 8) + t] = m;   // cand[8][16384], written once each
  }
}

// ---------------- gather + loss: 256 blocks x 256 thr; 64 n-rows/block
// 8-way ksp combine (fmax of packed floats), decode idx from mantissa bits,
// loss finalized here via 2 atomicAdds (slots zeroed by vq_prep).
__global__ __launch_bounds__(256)
void vq_gather(const float* __restrict__ cand, const float* __restrict__ w,
               const float* __restrict__ z, float* __restrict__ out)
{
  const int t = threadIdx.x;
  const int lane = t & 63;
  const int wv = t >> 6;                 // d-quarter
  const int n = blockIdx.x * 64 + lane;
  float m = cand[n];
#pragma unroll
  for (int k = 1; k < 8; ++k) m = fmaxf(m, cand[(k << 14) + n]);
  const int idx = (int)(__float_as_uint(m) & 8191u);
  const int b = n >> 10, hw = n & 1023;
  const size_t zb = ((size_t)b << 16) | (unsigned)hw;
  const float4* wr = (const float4*)(w + ((size_t)idx << 6));
  float sq = 0.0f;
#pragma unroll
  for (int q = 0; q < 4; ++q) {
    const float4 wvv = wr[(wv << 2) + q];
    const int d0 = (wv << 4) + (q << 2);
#pragma unroll
    for (int j = 0; j < 4; ++j) {
      const float wc = (j == 0) ? wvv.x : (j == 1) ? wvv.y : (j == 2) ? wvv.z : wvv.w;
      const size_t o = zb + ((size_t)(d0 + j) << 10);
      const float df = wc - z[o];
      sq += df * df;
      out[o] = wc;
    }
  }
#pragma unroll
  for (int s2 = 1; s2 < 64; s2 <<= 1) sq += __shfl_xor(sq, s2);
  __shared__ float ps[4];
  if (lane == 0) ps[wv] = sq;
  __syncthreads();
  if (t == 0) {
    const float s = (ps[0] + ps[1] + ps[2] + ps[3]) * (1.0f / 1048576.0f);
    atomicAdd(out + 1048576, 0.25f * s);   // commitment (BETA=0.25)
    atomicAdd(out + 1048577, s);           // codebook
  }
}

extern "C" void kernel_launch(void* const* d_in, const int* in_sizes, int n_in,
                              void* d_out, int out_size, void* d_ws, size_t ws_size,
                              hipStream_t stream)
{
  (void)in_sizes; (void)n_in; (void)out_size; (void)ws_size;
  const float* z = (const float*)d_in[0];
  const float* w = (const float*)d_in[1];
  float* out = (float*)d_out;
  char* ws = (char*)d_ws;
  float* cand = (float*)ws;                                     // 512 KB (8 x 16384 f32)
  __bf16* wbf = (__bf16*)(ws + 524288);                         // 1 MB
  float* wnneg = (float*)(ws + 524288 + 1048576);               // 32 KB

  vq_prep<<<2048, 256, 0, stream>>>(w, wbf, wnneg, out);
  vq_argmax<<<512, 512, 0, stream>>>(z, wbf, wnneg, cand);
  vq_gather<<<256, 256, 0, stream>>>(cand, w, z, out);
}

// Round 2
// 44.162 us; speedup vs baseline: 1.0162x; 1.0162x over previous
//
#include <hip/hip_runtime.h>
#include <hip/hip_bf16.h>
#include <stdint.h>

// VectorQuantizer: N=16384 vectors (D=64), K=8192 codes.
// score[n][k] = z_n.w_k - 0.5*||w_k||^2 (monotone in distance); idx = argmax.
// out[0..1048576) = quantized NCHW ; out[1048576] = 0.25*mse ; out[1048577] = mse

typedef __bf16 bf16x8 __attribute__((ext_vector_type(8)));
typedef float f32x16 __attribute__((ext_vector_type(16)));
typedef unsigned int u32x4 __attribute__((ext_vector_type(4)));

// ---------------- prep
// blocks 0..2047   : wbf = bf16(w), wnneg = -0.5||w||^2, zero loss slots
// blocks 2048..2111: zt = bf16(z) transposed into MFMA-fragment order:
//   zt byte addr(n, dc) = ((n>>5)*8 + dc)*512 + (n&31)*16, dc = d-chunk of 8
//   (so argmax loads fragments with fully-coalesced dwordx4: lanes rA stride 16B)
__global__ __launch_bounds__(256)
void vq_prep(const float* __restrict__ w, const float* __restrict__ z,
             __bf16* __restrict__ wbf, float* __restrict__ wnneg,
             __bf16* __restrict__ zt, float* __restrict__ out)
{
  const int t = threadIdx.x;
  if (blockIdx.x < 2048) {
    const int i = blockIdx.x * 256 + t;
    const float v = w[i];
    wbf[i] = (__bf16)v;
    float s = v * v;
#pragma unroll
    for (int m = 1; m < 64; m <<= 1) s += __shfl_xor(s, m);
    if ((t & 63) == 0) wnneg[i >> 6] = -0.5f * s;
    if (blockIdx.x == 0 && t < 2) out[1048576 + t] = 0.0f;
  } else {
    const int bid2 = blockIdx.x - 2048;          // 0..63; 256 rows each
    const int b = bid2 >> 2;
    const int hw = ((bid2 & 3) << 8) + t;        // this thread's z-row (within b)
    const float* zp = z + (((size_t)b) << 16) + hw;          // stride 1024 per d
    // out: nblk = bid2*8 + (t>>5), rowin = t&31
    char* ob = (char*)zt + ((((size_t)bid2 << 3) + (t >> 5)) << 12) + ((t & 31) << 4);
#pragma unroll
    for (int dc = 0; dc < 8; ++dc) {
      u32x4 pkt;
#pragma unroll
      for (int q = 0; q < 4; ++q) {
        const float a0 = zp[((size_t)(dc * 8 + q * 2)) << 10];
        const float a1 = zp[((size_t)(dc * 8 + q * 2 + 1)) << 10];
        const unsigned short h0 = __builtin_bit_cast(unsigned short, (__bf16)a0);
        const unsigned short h1 = __builtin_bit_cast(unsigned short, (__bf16)a1);
        pkt[q] = (unsigned)h0 | ((unsigned)h1 << 16);
      }
      *(u32x4*)(ob + (dc << 9)) = pkt;
    }
  }
}

// ---------------- argmax: pure 8-iter w-pipeline (NBUF=4, prefetch depth 3)
// grid 512: ksp = bid&7 (1024-code slice -> XCD-local L2), zgrp = bid>>3 (256 rows)
// 8 waves: ch = wv>>1 (code quarter, 256 codes), rg = wv&1 (row half, 128 rows)
// zf fragments come straight from zt via 16 coalesced global dwordx4 (no z LDS).
__global__ __launch_bounds__(512, 2)
void vq_argmax(const __bf16* __restrict__ zt, const __bf16* __restrict__ wbf,
               const float* __restrict__ wnneg, float* __restrict__ cand)
{
  __shared__ __align__(16) char bufs[4][16384];
  __shared__ __align__(16) float wnl[1024];
  const int t = threadIdx.x;
  const int lane = t & 63, wv = t >> 6;
  const int hi = lane >> 5, hi4 = hi << 2, rA = lane & 31;
  const int ksp = blockIdx.x & 7, zgrp = blockIdx.x >> 3;
  const int kbase = ksp << 10;
  const int ch = wv >> 1, rg = wv & 1;

  // stage -0.5||w||^2 slice (4 KB)
  ((float2*)wnl)[t] = ((const float2*)(wnneg + kbase))[t];
  asm volatile("s_waitcnt lgkmcnt(0)" ::: "memory");

  // zf fragments: rows (rg*128 + nt*32 + rA), d-chunk dc = 2c+hi
  bf16x8 zf[4][4];   // [row-tile][k-slice]
  {
    const char* zb = (const char*)zt
        + ((((size_t)(zgrp << 3)) + (rg << 2)) << 12) + (hi << 9) + (rA << 4);
#pragma unroll
    for (int nt = 0; nt < 4; ++nt)
#pragma unroll
      for (int c = 0; c < 4; ++c)
        zf[nt][c] = *(const bf16x8*)(zb + (nt << 12) + (c << 10));
  }

  // w staging: per stage 4 quarter-tiles of 32 codes, pre-swizzled source
  // (XOR row&7 into 16B slot); persistent src pointers advance s*4096.
  const int tt = t & 255;
  const int row = tt >> 3, slot = (tt & 7) ^ (row & 7);
  const int q0 = t >> 8;                        // 0 or 1
  const char* s0p = (const char*)wbf
      + (((size_t)(kbase + (q0 << 8) + row)) << 7) + (slot << 4);
  const char* s1p = s0p + ((size_t)2 << 15);    // quarters q0+2
  const int doff0 = (q0 << 12) + ((wv & 3) << 10);
  const int doff1 = ((q0 + 2) << 12) + ((wv & 3) << 10);

  auto STAGE = [&](int s) {
    char* buf = &bufs[s & 3][0];
    __builtin_amdgcn_global_load_lds(
        (const __attribute__((address_space(1))) void*)(s0p + ((size_t)s << 12)),
        (__attribute__((address_space(3))) void*)(buf + doff0), 16, 0, 0);
    __builtin_amdgcn_global_load_lds(
        (const __attribute__((address_space(1))) void*)(s1p + ((size_t)s << 12)),
        (__attribute__((address_space(3))) void*)(buf + doff1), 16, 0, 0);
  };

  STAGE(0); STAGE(1); STAGE(2);

  // main loop: 32 codes x 4 row-tiles per iter. Branchless packed argmax:
  // score truncated to 10 mantissa bits, code id in bits 0..12.
  float bestpk[4] = {-3.0e38f, -3.0e38f, -3.0e38f, -3.0e38f};

#pragma unroll 1
  for (int i = 0; i < 8; ++i) {
    if (i < 6)      asm volatile("s_waitcnt vmcnt(4)" ::: "memory");
    else if (i == 6) asm volatile("s_waitcnt vmcnt(2)" ::: "memory");
    else            asm volatile("s_waitcnt vmcnt(0)" ::: "memory");
    asm volatile("s_barrier" ::: "memory");

    const char* tb = &bufs[i & 3][0] + (ch << 12);
    bf16x8 af[4];
#pragma unroll
    for (int ks = 0; ks < 4; ++ks) {
      const int c16 = (ks << 1) + hi;
      af[ks] = *(const bf16x8*)(tb + (rA << 7) + ((c16 ^ (rA & 7)) << 4));
    }

    const int kloc = (ch << 8) + (i << 5);
    f32x16 acc[4];
#pragma unroll
    for (int nt = 0; nt < 4; ++nt) {
      const float4 b0 = *(const float4*)(wnl + kloc + hi4);
      const float4 b1 = *(const float4*)(wnl + kloc + 8 + hi4);
      const float4 b2 = *(const float4*)(wnl + kloc + 16 + hi4);
      const float4 b3 = *(const float4*)(wnl + kloc + 24 + hi4);
      acc[nt] = (f32x16){b0.x, b0.y, b0.z, b0.w, b1.x, b1.y, b1.z, b1.w,
                         b2.x, b2.y, b2.z, b2.w, b3.x, b3.y, b3.z, b3.w};
    }
#pragma unroll
    for (int ks = 0; ks < 4; ++ks) {
#pragma unroll
      for (int nt = 0; nt < 4; ++nt)
        acc[nt] = __builtin_amdgcn_mfma_f32_32x32x16_bf16(af[ks], zf[nt][ks], acc[nt], 0, 0, 0);
    }

    const unsigned khw = (unsigned)(kbase + kloc + hi4);
#pragma unroll
    for (int nt = 0; nt < 4; ++nt) {
      const f32x16 a = acc[nt];
      float pk[16];
#pragma unroll
      for (int r = 0; r < 16; ++r) {
        const unsigned id = khw + (unsigned)((r & 3) + ((r >> 2) << 3));
        pk[r] = __uint_as_float((__float_as_uint(a[r]) & 0xFFFFE000u) | id);
      }
      const float g0 = fmaxf(fmaxf(pk[0], pk[1]), pk[2]);
      const float g1 = fmaxf(fmaxf(pk[3], pk[4]), pk[5]);
      const float g2 = fmaxf(fmaxf(pk[6], pk[7]), pk[8]);
      const float g3 = fmaxf(fmaxf(pk[9], pk[10]), pk[11]);
      const float g4 = fmaxf(fmaxf(pk[12], pk[13]), pk[14]);
      const float h0 = fmaxf(fmaxf(g0, g1), g2);
      const float h1 = fmaxf(fmaxf(g3, g4), pk[15]);
      bestpk[nt] = fmaxf(bestpk[nt], fmaxf(h0, h1));
    }
    if (i < 5) STAGE(i + 3);
  }

  // combine hi halves (lanes l, l+32 hold the same z-row), then the 4
  // ch-quarters through LDS (reuse wnl); publish one plain store per row.
  float bp4[4];
#pragma unroll
  for (int nt = 0; nt < 4; ++nt)
    bp4[nt] = fmaxf(bestpk[nt], __shfl_down(bestpk[nt], 32));

  __syncthreads();                 // all waves done with wnl/bufs
  if (lane < 32) {
#pragma unroll
    for (int nt = 0; nt < 4; ++nt)
      wnl[(ch << 8) + (rg << 7) + (nt << 5) + rA] = bp4[nt];
  }
  __syncthreads();
  if (t < 256) {
    const float m = fmaxf(fmaxf(wnl[t], wnl[256 + t]),
                          fmaxf(wnl[512 + t], wnl[768 + t]));
    cand[(ksp << 14) + (zgrp << 8) + t] = m;   // cand[8][16384]
  }
}

// ---------------- gather + loss: 256 blocks x 256 thr; 64 n-rows/block
__global__ __launch_bounds__(256)
void vq_gather(const float* __restrict__ cand, const float* __restrict__ w,
               const float* __restrict__ z, float* __restrict__ out)
{
  const int t = threadIdx.x;
  const int lane = t & 63;
  const int wv = t >> 6;                 // d-quarter
  const int n = blockIdx.x * 64 + lane;
  float m = cand[n];
#pragma unroll
  for (int k = 1; k < 8; ++k) m = fmaxf(m, cand[(k << 14) + n]);
  const int idx = (int)(__float_as_uint(m) & 8191u);
  const int b = n >> 10, hw = n & 1023;
  const size_t zb = ((size_t)b << 16) | (unsigned)hw;
  const float4* wr = (const float4*)(w + ((size_t)idx << 6));
  float sq = 0.0f;
#pragma unroll
  for (int q = 0; q < 4; ++q) {
    const float4 wvv = wr[(wv << 2) + q];
    const int d0 = (wv << 4) + (q << 2);
#pragma unroll
    for (int j = 0; j < 4; ++j) {
      const float wc = (j == 0) ? wvv.x : (j == 1) ? wvv.y : (j == 2) ? wvv.z : wvv.w;
      const size_t o = zb + ((size_t)(d0 + j) << 10);
      const float df = wc - z[o];
      sq += df * df;
      out[o] = wc;
    }
  }
#pragma unroll
  for (int s2 = 1; s2 < 64; s2 <<= 1) sq += __shfl_xor(sq, s2);
  __shared__ float ps[4];
  if (lane == 0) ps[wv] = sq;
  __syncthreads();
  if (t == 0) {
    const float s = (ps[0] + ps[1] + ps[2] + ps[3]) * (1.0f / 1048576.0f);
    atomicAdd(out + 1048576, 0.25f * s);   // commitment (BETA=0.25)
    atomicAdd(out + 1048577, s);           // codebook
  }
}

extern "C" void kernel_launch(void* const* d_in, const int* in_sizes, int n_in,
                              void* d_out, int out_size, void* d_ws, size_t ws_size,
                              hipStream_t stream)
{
  (void)in_sizes; (void)n_in; (void)out_size; (void)ws_size;
  const float* z = (const float*)d_in[0];
  const float* w = (const float*)d_in[1];
  float* out = (float*)d_out;
  char* ws = (char*)d_ws;
  float* cand = (float*)ws;                                     // 512 KB (8 x 16384 f32)
  __bf16* wbf = (__bf16*)(ws + 524288);                         // 1 MB
  float* wnneg = (float*)(ws + 524288 + 1048576);               // 32 KB
  __bf16* zt = (__bf16*)(ws + 524288 + 1048576 + 32768);        // 2 MB

  vq_prep<<<2112, 256, 0, stream>>>(w, z, wbf, wnneg, zt, out);
  vq_argmax<<<512, 512, 0, stream>>>(zt, wbf, wnneg, cand);
  vq_gather<<<256, 256, 0, stream>>>(cand, w, z, out);
}